// Round 11
// baseline (723.092 us; speedup 1.0000x reference)
//
#include <hip/hip_runtime.h>
#include <hip/hip_bf16.h>

#define D 128
#define NPB 64
#define EPB1 1024          // edges per pass1/hist1 block
#define BDST 32            // dsts per bucket (bucket = dst >> 5)
#define MAXBINS 2048       // LDS cursor capacity (nb1 = ceil(n_dst/32) = 1563)
#define NCHUNK 8           // scan chunks along the block axis

typedef __attribute__((ext_vector_type(8))) short short8;   // 8 bf16 (4 VGPRs)
typedef __attribute__((ext_vector_type(4))) float f32x4;

static __device__ __forceinline__ unsigned short f32_to_bf16(float f) {
    unsigned int u = __float_as_uint(f);
    u = (u + 0x7FFFu + ((u >> 16) & 1u)) >> 16;   // RNE
    return (unsigned short)u;
}
static __device__ __forceinline__ float bf16lo(unsigned int r) {
    return __uint_as_float(r << 16);
}
static __device__ __forceinline__ float bf16hi(unsigned int r) {
    return __uint_as_float(r & 0xFFFF0000u);
}

// ---------------------------------------------------------------------------
// K0: convert w_embed rows into MFMA B-fragment layout (bf16), two sets.
// ---------------------------------------------------------------------------
__global__ void __launch_bounds__(256)
wconv_kernel(const float* __restrict__ w_embed, unsigned short* __restrict__ w_frag)
{
    int t = blockIdx.x * 256 + threadIdx.x;     // 4096 lane-frags total
    if (t >= 4096) return;
    int set  = t >> 11;
    int ks   = (t >> 9) & 3;
    int nt   = (t >> 6) & 7;
    int lane = t & 63;
    int wrow0 = set ? 130 : 0;
    int col   = nt * 16 + (lane & 15);
    int kbase = ks * 32 + (lane >> 4) * 8;
    unsigned short* dst = w_frag + (size_t)t * 8;
#pragma unroll
    for (int j = 0; j < 8; ++j)
        dst[j] = f32_to_bf16(w_embed[(size_t)(wrow0 + kbase + j) * D + col]);
}

// ---------------------------------------------------------------------------
// K1: fused MFMA node projection.
//     srcp written in SPLIT-PAIR layout: uint word l of a row = {col l, col l+64}
//     (bf16 lo/hi) so p2agg's one uint gather feeds two conflict-free ds_adds.
//     dstp written in normal layout.
// ---------------------------------------------------------------------------
__global__ void __launch_bounds__(256)
proj_both_kernel(const float* __restrict__ src_feat, const float* __restrict__ dst_feat,
                 const unsigned short* __restrict__ wfrag_base,
                 const float* __restrict__ w_att,
                 int n_src, int n_dst, int nblk_src,
                 unsigned short* __restrict__ srcp, unsigned short* __restrict__ dstp,
                 float* __restrict__ src_att, float* __restrict__ dst_att)
{
    const bool is_src = (blockIdx.x < nblk_src);
    const float* feats = is_src ? src_feat : dst_feat;
    const unsigned short* wfrag = is_src ? wfrag_base : wfrag_base + 16384;
    const int wrow = is_src ? 0 : 130;
    const int n_nodes = is_src ? n_src : n_dst;
    unsigned short* proj = is_src ? srcp : dstp;
    float* att = is_src ? src_att : dst_att;
    const int blk = is_src ? blockIdx.x : blockIdx.x - nblk_src;

    __shared__ unsigned short s_tile[NPB * D];   // 16 KB, swizzled
    __shared__ float s_red[NPB][4];

    const int tid = threadIdx.x;
    const int node0 = blk * NPB;

#pragma unroll
    for (int it = 0; it < 8; ++it) {
        int idx = it * 256 + tid;          // 2048 float4 groups
        int row = idx >> 5, c4 = idx & 31;
        int n = node0 + row;
        float4 v = (n < n_nodes)
                 ? *reinterpret_cast<const float4*>(&feats[(size_t)n * D + c4 * 4])
                 : make_float4(0.f, 0.f, 0.f, 0.f);
        unsigned short h[4];
        h[0] = f32_to_bf16(v.x); h[1] = f32_to_bf16(v.y);
        h[2] = f32_to_bf16(v.z); h[3] = f32_to_bf16(v.w);
        int byte = row * 256 + c4 * 8;
        byte ^= (row & 7) << 4;
        *reinterpret_cast<ushort4*>((char*)s_tile + byte) = *reinterpret_cast<ushort4*>(h);
    }
    __syncthreads();

    const int wv = tid >> 6, lane = tid & 63;

    f32x4 acc[8];
#pragma unroll
    for (int i = 0; i < 8; ++i) acc[i] = {0.f, 0.f, 0.f, 0.f};

    const int arow = wv * 16 + (lane & 15);
#pragma unroll
    for (int ks = 0; ks < 4; ++ks) {
        int abyte = arow * 256 + ks * 64 + (lane >> 4) * 16;
        abyte ^= (arow & 7) << 4;
        short8 a = *reinterpret_cast<const short8*>((char*)s_tile + abyte);
#pragma unroll
        for (int nt = 0; nt < 8; ++nt) {
            short8 b = *reinterpret_cast<const short8*>(wfrag + ((size_t)(ks * 8 + nt) * 64 + lane) * 8);
            acc[nt] = __builtin_amdgcn_mfma_f32_16x16x32_bf16(a, b, acc[nt], 0, 0, 0);
        }
    }

    // C/D: col = lane&15, row = (lane>>4)*4 + r
#pragma unroll
    for (int nt = 0; nt < 8; ++nt) {
        const int c = nt * 16 + (lane & 15);
        const size_t off = is_src
            ? ((c < 64) ? (size_t)(4 * c) : (size_t)(4 * (c - 64) + 2))
            : (size_t)(2 * c);
#pragma unroll
        for (int r = 0; r < 4; ++r) {
            int node = node0 + wv * 16 + (lane >> 4) * 4 + r;
            if (node < n_nodes)
                *reinterpret_cast<unsigned short*>((char*)proj + (size_t)node * 256 + off)
                    = f32_to_bf16(acc[nt][r]);
        }
    }

    // att scalar: 256 threads = 64 nodes x 4 k-quarters (reads swizzled LDS)
    const int na = tid & 63, kq = tid >> 6;
    float p = 0.f;
#pragma unroll
    for (int k = kq * 32; k < kq * 32 + 32; ++k) {
        int byte = (na * 256 + k * 2) ^ ((na & 7) << 4);
        unsigned short h = *reinterpret_cast<const unsigned short*>((char*)s_tile + byte);
        p += __uint_as_float(((unsigned int)h) << 16) * w_att[wrow + k];
    }
    s_red[na][kq] = p;
    __syncthreads();
    if (tid < NPB) {
        int n = node0 + tid;
        if (n < n_nodes)
            att[n] = s_red[tid][0] + s_red[tid][1] + s_red[tid][2] + s_red[tid][3];
    }
}

// ---------------------------------------------------------------------------
// K_h1: per-block bucket histogram (dst>>5), LDS-binned; bb block-major.
// ---------------------------------------------------------------------------
__global__ void __launch_bounds__(256)
hist1_kernel(const int* __restrict__ edst, int* __restrict__ bb,
             int n_edge, int nblk1, int nb1)
{
    __shared__ int bins[MAXBINS];
    const int tid = threadIdx.x, blk = blockIdx.x;
    for (int i = tid; i < nb1; i += 256) bins[i] = 0;
    __syncthreads();
#pragma unroll
    for (int it = 0; it < EPB1 / 256; ++it) {
        int e = blk * EPB1 + it * 256 + tid;
        if (e < n_edge) atomicAdd(&bins[((unsigned)edst[e]) >> 5], 1);
    }
    __syncthreads();
    for (int i = tid; i < nb1; i += 256) bb[(size_t)blk * nb1 + i] = bins[i];
}

// ---------------------------------------------------------------------------
// K_cs1: chunk sums (read-only, coalesced across adjacent bins).
// ---------------------------------------------------------------------------
__global__ void __launch_bounds__(256)
chunksum_kernel(const int* __restrict__ bb, int* __restrict__ cs,
                int nb1, int nblk1, int cb)
{
    int t = blockIdx.x * 256 + threadIdx.x;
    if (t >= nb1 * NCHUNK) return;
    int c = t / nb1, bin = t - c * nb1;
    int b0 = c * cb, b1 = min(b0 + cb, nblk1);
    int s = 0;
    for (int blk = b0; blk < b1; ++blk)
        s += bb[(size_t)blk * nb1 + bin];
    cs[(size_t)c * nb1 + bin] = s;
}

// ---------------------------------------------------------------------------
// K_ms: midscan (single block): per-bin chunk scan + cross-bin scan.
// ---------------------------------------------------------------------------
__global__ void __launch_bounds__(1024)
midscan_kernel(int* __restrict__ cs, int* __restrict__ binstart,
               int nb1, int n_edge)
{
    __shared__ int s_tot[MAXBINS];
    __shared__ int s_w[16];
    __shared__ int s_total;
    __shared__ int s_carry;
    const int tid = threadIdx.x;
    const int lane = tid & 63, wid = tid >> 6;

    for (int bin = tid; bin < nb1; bin += 1024) {
        int run = 0;
#pragma unroll
        for (int c = 0; c < NCHUNK; ++c) {
            size_t idx = (size_t)c * nb1 + bin;
            int v = cs[idx];
            cs[idx] = run;
            run += v;
        }
        s_tot[bin] = run;
    }
    if (tid == 0) s_carry = 0;
    __syncthreads();

    for (int base = 0; base < nb1; base += 1024) {
        int idx = base + tid;
        int v = (idx < nb1) ? s_tot[idx] : 0;
        int x = v;
#pragma unroll
        for (int off = 1; off < 64; off <<= 1) {
            int y = __shfl_up(x, off);
            if (lane >= off) x += y;
        }
        if (lane == 63) s_w[wid] = x;
        __syncthreads();
        if (tid < 16) {
            int w = s_w[tid];
            int xi = w;
#pragma unroll
            for (int off = 1; off < 16; off <<= 1) {
                int y = __shfl_up(xi, off);
                if (tid >= off) xi += y;
            }
            if (tid == 15) s_total = xi;
            s_w[tid] = xi - w;   // exclusive wave offset
        }
        __syncthreads();
        if (idx < nb1) binstart[idx] = s_carry + s_w[wid] + (x - v);
        __syncthreads();
        if (tid == 0) s_carry += s_total;
        __syncthreads();
    }
    if (tid == 0) binstart[nb1] = n_edge;
}

// ---------------------------------------------------------------------------
// K_cw: chunk write-back, 8-deep batched (alias-broken).
// ---------------------------------------------------------------------------
__global__ void __launch_bounds__(256)
chunkwrite_kernel(int* __restrict__ bb, const int* __restrict__ cs,
                  int nb1, int nblk1, int cb)
{
    int t = blockIdx.x * 256 + threadIdx.x;
    if (t >= nb1 * NCHUNK) return;
    int c = t / nb1, bin = t - c * nb1;
    int b0 = c * cb, b1 = min(b0 + cb, nblk1);
    int carry = cs[(size_t)c * nb1 + bin];
    for (int blk0 = b0; blk0 < b1; blk0 += 8) {
        int v[8];
#pragma unroll
        for (int j = 0; j < 8; ++j) {
            int blk = blk0 + j;
            v[j] = (blk < b1) ? bb[(size_t)blk * nb1 + bin] : 0;
        }
#pragma unroll
        for (int j = 0; j < 8; ++j) {
            int blk = blk0 + j;
            if (blk < b1) bb[(size_t)blk * nb1 + bin] = carry;
            carry += v[j];
        }
    }
}

// ---------------------------------------------------------------------------
// K_p1: phase-split scatter. 4 edges/thread: batched loads -> 8 independent
//     att gathers -> exps -> 4 LDS atomics -> 4 stores.
//     meta1 = {src | (dlow<<24), ew, d0, d1}, dlow = d&31.
// ---------------------------------------------------------------------------
__global__ void __launch_bounds__(256)
pass1_kernel(const int* __restrict__ esrc, const int* __restrict__ edst,
             const float* __restrict__ dist,
             const float* __restrict__ src_att, const float* __restrict__ dst_att,
             const float* __restrict__ w_att,
             const int* __restrict__ bb, const int* __restrict__ binstart,
             float4* __restrict__ meta1, int n_edge, int nblk1, int nb1)
{
    __shared__ int cur[MAXBINS];
    const int tid = threadIdx.x, blk = blockIdx.x;
    for (int i = tid; i < nb1; i += 256)
        cur[i] = binstart[i] + bb[(size_t)blk * nb1 + i];
    __syncthreads();

    const float wa0 = w_att[128], wa1 = w_att[129];
    const int e0 = blk * EPB1 + tid * 4;
    if (e0 + 4 <= n_edge) {
        // phase A: batched coalesced loads
        int4 s4 = *reinterpret_cast<const int4*>(&esrc[e0]);
        int4 d4 = *reinterpret_cast<const int4*>(&edst[e0]);
        float4 da = *reinterpret_cast<const float4*>(&dist[2 * (size_t)e0]);
        float4 db = *reinterpret_cast<const float4*>(&dist[2 * (size_t)e0 + 4]);
        // 8 independent gathers
        float sa0 = src_att[s4.x], sa1 = src_att[s4.y];
        float sa2 = src_att[s4.z], sa3 = src_att[s4.w];
        float ta0 = dst_att[d4.x], ta1 = dst_att[d4.y];
        float ta2 = dst_att[d4.z], ta3 = dst_att[d4.w];
        // scores
        float c0 = sa0 + ta0 + da.x * wa0 + da.y * wa1;
        float c1 = sa1 + ta1 + da.z * wa0 + da.w * wa1;
        float c2 = sa2 + ta2 + db.x * wa0 + db.y * wa1;
        float c3 = sa3 + ta3 + db.z * wa0 + db.w * wa1;
        c0 = (c0 >= 0.f) ? c0 : 0.2f * c0;
        c1 = (c1 >= 0.f) ? c1 : 0.2f * c1;
        c2 = (c2 >= 0.f) ? c2 : 0.2f * c2;
        c3 = (c3 >= 0.f) ? c3 : 0.2f * c3;
        float w0 = __expf(c0), w1 = __expf(c1), w2 = __expf(c2), w3 = __expf(c3);
        // phase B: LDS rank atomics
        int p0 = atomicAdd(&cur[((unsigned)d4.x) >> 5], 1);
        int p1 = atomicAdd(&cur[((unsigned)d4.y) >> 5], 1);
        int p2 = atomicAdd(&cur[((unsigned)d4.z) >> 5], 1);
        int p3 = atomicAdd(&cur[((unsigned)d4.w) >> 5], 1);
        // phase C: scattered stores
        meta1[p0] = make_float4(__int_as_float(s4.x | ((d4.x & 31) << 24)), w0, da.x, da.y);
        meta1[p1] = make_float4(__int_as_float(s4.y | ((d4.y & 31) << 24)), w1, da.z, da.w);
        meta1[p2] = make_float4(__int_as_float(s4.z | ((d4.z & 31) << 24)), w2, db.x, db.y);
        meta1[p3] = make_float4(__int_as_float(s4.w | ((d4.w & 31) << 24)), w3, db.z, db.w);
    } else {
        for (int e = e0; e < n_edge; ++e) {
            int s = esrc[e];
            int d = edst[e];
            float2 dd = *reinterpret_cast<const float2*>(&dist[2 * (size_t)e]);
            float sc = src_att[s] + dst_att[d] + dd.x * wa0 + dd.y * wa1;
            sc = (sc >= 0.f) ? sc : 0.2f * sc;
            float ew = __expf(sc);
            int pos = atomicAdd(&cur[((unsigned)d) >> 5], 1);
            meta1[pos] = make_float4(__int_as_float(s | ((d & 31) << 24)), ew, dd.x, dd.y);
        }
    }
}

// ---------------------------------------------------------------------------
// K_p2agg: edge-parallel aggregation via LDS-atomic accumulators (no sort).
//     One block per 32-dst bucket; 4 waves stream edges; conflict-free ds_add
//     thanks to srcp split-pair layout. Any bucket size handled.
// ---------------------------------------------------------------------------
__global__ void __launch_bounds__(256)
p2agg_kernel(const float4* __restrict__ meta1, const int* __restrict__ binstart,
             const unsigned short* __restrict__ srcp,   // split-pair bf16 [n_src,128]
             const unsigned short* __restrict__ dstp,   // normal bf16 [n_dst,128]
             const float* __restrict__ w_embed,
             float* __restrict__ out, int n_dst)
{
    __shared__ float s_acc[BDST][D];        // 16 KB
    __shared__ float s_sums[3 * BDST];      // sw, swd0, swd1

    const int tid = threadIdx.x;
    const int b = blockIdx.x;
    const int lane = tid & 63, wv = tid >> 6;   // 4 waves

    // zero accumulators
#pragma unroll
    for (int k = 0; k < 4; ++k)
        reinterpret_cast<float4*>(&s_acc[0][0])[k * 256 + tid] =
            make_float4(0.f, 0.f, 0.f, 0.f);
    if (tid < 3 * BDST) s_sums[tid] = 0.f;
    __syncthreads();

    const int bstart = __builtin_amdgcn_readfirstlane(binstart[b]);
    const int bend   = __builtin_amdgcn_readfirstlane(binstart[b + 1]);

    // sum fan-out: lanes 0..11 handle (edge 0..3) x (type 0..2)
    const int eidx = lane / 3;      // 0..3 (lane<12)
    const int typ  = lane - eidx * 3;

#define EDGE_ADD(m)                                                              \
    {                                                                            \
        int bits_ = __float_as_int((m).x);                                       \
        unsigned int r_ = *reinterpret_cast<const unsigned int*>(                \
            (const char*)srcp + (size_t)(bits_ & 0xFFFFFF) * 256 + 4 * lane);    \
        int dl_ = ((unsigned)bits_) >> 24;                                       \
        atomicAdd(&s_acc[dl_][lane],      (m).y * bf16lo(r_));                   \
        atomicAdd(&s_acc[dl_][lane + 64], (m).y * bf16hi(r_));                   \
    }

    int i = bstart + wv * 4;
    for (; i + 4 <= bend; i += 16) {
        float4 m0 = meta1[i + 0];
        float4 m1 = meta1[i + 1];
        float4 m2 = meta1[i + 2];
        float4 m3 = meta1[i + 3];
        EDGE_ADD(m0) EDGE_ADD(m1) EDGE_ADD(m2) EDGE_ADD(m3)
        if (lane < 12) {
            float4 mm = (eidx == 0) ? m0 : (eidx == 1) ? m1 : (eidx == 2) ? m2 : m3;
            int dl = ((unsigned)__float_as_int(mm.x)) >> 24;
            float val = (typ == 0) ? mm.y : (typ == 1) ? mm.y * mm.z : mm.y * mm.w;
            atomicAdd(&s_sums[typ * BDST + dl], val);
        }
    }
    for (int j = i; j < min(i + 4, bend); ++j) {
        float4 m0 = meta1[j];
        EDGE_ADD(m0)
        if (lane < 3) {
            int dl = ((unsigned)__float_as_int(m0.x)) >> 24;
            float val = (lane == 0) ? m0.y : (lane == 1) ? m0.y * m0.z : m0.y * m0.w;
            atomicAdd(&s_sums[lane * BDST + dl], val);
        }
    }
#undef EDGE_ADD
    __syncthreads();

    // output: 8 iterations x 256 threads = 2048 col-pairs = 32 dsts x 64 pairs
#pragma unroll
    for (int k = 0; k < 8; ++k) {
        int idx = k * 256 + tid;
        int dloc = idx >> 6;            // 0..31
        int cp = idx & 63;              // col pair: cols 2cp, 2cp+1
        int gd = b * BDST + dloc;
        if (gd >= n_dst) continue;
        float sw = s_sums[dloc];
        float2 o;
        if (sw == 0.f) {
            o = make_float2(0.f, 0.f);
        } else {
            float inv = 1.f / sw;
            float s0 = s_sums[BDST + dloc], s1 = s_sums[2 * BDST + dloc];
            float2 wd0 = *reinterpret_cast<const float2*>(&w_embed[128 * D + 2 * cp]);
            float2 wd1 = *reinterpret_cast<const float2*>(&w_embed[129 * D + 2 * cp]);
            unsigned int rd = *reinterpret_cast<const unsigned int*>(
                &dstp[(size_t)gd * D + 2 * cp]);
            float ov0 = (s_acc[dloc][2 * cp]     + s0 * wd0.x + s1 * wd1.x) * inv + bf16lo(rd);
            float ov1 = (s_acc[dloc][2 * cp + 1] + s0 * wd0.y + s1 * wd1.y) * inv + bf16hi(rd);
            o = make_float2(fmaxf(ov0, 0.f), fmaxf(ov1, 0.f));
        }
        *reinterpret_cast<float2*>(&out[(size_t)gd * D + 2 * cp]) = o;
    }
}

// ---------------------------------------------------------------------------
extern "C" void kernel_launch(void* const* d_in, const int* in_sizes, int n_in,
                              void* d_out, int out_size, void* d_ws, size_t ws_size,
                              hipStream_t stream)
{
    const float* src_feat = (const float*)d_in[0];   // [N_SRC,128]
    const int*   esrc     = (const int*)d_in[1];     // [E]
    const float* dst_feat = (const float*)d_in[2];   // [N_DST,128]
    const int*   edst     = (const int*)d_in[3];     // [E]
    const float* dist     = (const float*)d_in[4];   // [E,2]
    const float* w_att    = (const float*)d_in[5];   // [258]
    const float* w_embed  = (const float*)d_in[6];   // [258,128]

    const int n_src  = in_sizes[0] / D;
    const int n_edge = in_sizes[1];
    const int n_dst  = in_sizes[2] / D;

    const int nb1   = (n_dst + BDST - 1) / BDST;     // buckets (1563)
    const int nblk1 = (n_edge + EPB1 - 1) / EPB1;    // pass-1 blocks (782)
    const int cb    = (nblk1 + NCHUNK - 1) / NCHUNK; // blocks per scan chunk (98)
    const size_t n1 = (size_t)nb1 * nblk1;

    // ---- workspace carve-up (256B-aligned) ----
    char* p = (char*)d_ws;
    auto carve = [&p](size_t bytes) {
        char* r = p;
        p += (bytes + 255) & ~size_t(255);
        return r;
    };
    unsigned short* src_projb = (unsigned short*)carve((size_t)n_src * D * 2);  // split-pair bf16
    unsigned short* dst_projb = (unsigned short*)carve((size_t)n_dst * D * 2);  // bf16
    float* src_att   = (float*)carve((size_t)n_src * 4);
    float* dst_att   = (float*)carve((size_t)n_dst * 4);
    int*   bb        = (int*)carve(n1 * 4);
    int*   cs        = (int*)carve((size_t)NCHUNK * nb1 * 4);
    int*   binstart  = (int*)carve((size_t)(nb1 + 1) * 4);
    unsigned short* w_frag = (unsigned short*)carve(2 * 4 * 8 * 64 * 8 * 2);  // 64 KB
    float4* meta1    = (float4*)carve((size_t)n_edge * 16);
    (void)ws_size;

    // K0: W -> bf16 fragment layout
    wconv_kernel<<<16, 256, 0, stream>>>(w_embed, w_frag);

    // K1: fused MFMA node projections
    const int nblk_src = (n_src + NPB - 1) / NPB;
    const int nblk_dst = (n_dst + NPB - 1) / NPB;
    proj_both_kernel<<<nblk_src + nblk_dst, 256, 0, stream>>>(
        src_feat, dst_feat, w_frag, w_att, n_src, n_dst, nblk_src,
        src_projb, dst_projb, src_att, dst_att);

    // K_h1: bucket histogram per pass1-block (block-major, coalesced)
    hist1_kernel<<<nblk1, 256, 0, stream>>>(edst, bb, n_edge, nblk1, nb1);

    // K_cs1 / K_ms / K_cw: parallel column scan of bb + binstart
    const int nthr_cs = nb1 * NCHUNK;
    chunksum_kernel<<<(nthr_cs + 255) / 256, 256, 0, stream>>>(bb, cs, nb1, nblk1, cb);
    midscan_kernel<<<1, 1024, 0, stream>>>(cs, binstart, nb1, n_edge);
    chunkwrite_kernel<<<(nthr_cs + 255) / 256, 256, 0, stream>>>(bb, cs, nb1, nblk1, cb);

    // K_p1: score/exp + bucket scatter (phase-split ILP)
    pass1_kernel<<<nblk1, 256, 0, stream>>>(esrc, edst, dist, src_att, dst_att,
                                            w_att, bb, binstart, meta1,
                                            n_edge, nblk1, nb1);

    // K_p2agg: edge-parallel LDS-atomic aggregation
    p2agg_kernel<<<nb1, 256, 0, stream>>>(meta1, binstart, src_projb, dst_projb,
                                          w_embed, (float*)d_out, n_dst);
}

// Round 12
// 113.880 us; speedup vs baseline: 6.3496x; 6.3496x over previous
//
#include <hip/hip_runtime.h>
#include <hip/hip_bf16.h>

#define D 128
#define NPB 64
#define EPB1 2048          // edges per pass1/hist1 block
#define BDST 32            // dsts per fine bucket (bucket = dst >> 5)
#define CAP 1024           // max edges per bucket fast path (avg ~512)
#define MAXBINS 2048       // LDS cursor capacity (nb1 = ceil(n_dst/32) = 1563)
#define NCHUNK 8           // scan chunks along the block axis

typedef __attribute__((ext_vector_type(8))) short short8;   // 8 bf16 (4 VGPRs)
typedef __attribute__((ext_vector_type(4))) float f32x4;

static __device__ __forceinline__ unsigned short f32_to_bf16(float f) {
    unsigned int u = __float_as_uint(f);
    u = (u + 0x7FFFu + ((u >> 16) & 1u)) >> 16;   // RNE
    return (unsigned short)u;
}
static __device__ __forceinline__ float bf16lo(unsigned int r) {
    return __uint_as_float(r << 16);
}
static __device__ __forceinline__ float bf16hi(unsigned int r) {
    return __uint_as_float(r & 0xFFFF0000u);
}

// ---------------------------------------------------------------------------
// K0: convert w_embed rows into MFMA B-fragment layout (bf16), two sets.
// ---------------------------------------------------------------------------
__global__ void __launch_bounds__(256)
wconv_kernel(const float* __restrict__ w_embed, unsigned short* __restrict__ w_frag)
{
    int t = blockIdx.x * 256 + threadIdx.x;     // 4096 lane-frags total
    if (t >= 4096) return;
    int set  = t >> 11;
    int ks   = (t >> 9) & 3;
    int nt   = (t >> 6) & 7;
    int lane = t & 63;
    int wrow0 = set ? 130 : 0;
    int col   = nt * 16 + (lane & 15);
    int kbase = ks * 32 + (lane >> 4) * 8;
    unsigned short* dst = w_frag + (size_t)t * 8;
#pragma unroll
    for (int j = 0; j < 8; ++j)
        dst[j] = f32_to_bf16(w_embed[(size_t)(wrow0 + kbase + j) * D + col]);
}

// ---------------------------------------------------------------------------
// K1: fused MFMA node projection (src blocks then dst blocks in one grid).
// ---------------------------------------------------------------------------
__global__ void __launch_bounds__(256)
proj_both_kernel(const float* __restrict__ src_feat, const float* __restrict__ dst_feat,
                 const unsigned short* __restrict__ wfrag_base,
                 const float* __restrict__ w_att,
                 int n_src, int n_dst, int nblk_src,
                 unsigned short* __restrict__ srcp, unsigned short* __restrict__ dstp,
                 float* __restrict__ src_att, float* __restrict__ dst_att)
{
    const bool is_src = (blockIdx.x < nblk_src);
    const float* feats = is_src ? src_feat : dst_feat;
    const unsigned short* wfrag = is_src ? wfrag_base : wfrag_base + 16384;
    const int wrow = is_src ? 0 : 130;
    const int n_nodes = is_src ? n_src : n_dst;
    unsigned short* proj = is_src ? srcp : dstp;
    float* att = is_src ? src_att : dst_att;
    const int blk = is_src ? blockIdx.x : blockIdx.x - nblk_src;

    __shared__ unsigned short s_tile[NPB * D];   // 16 KB, swizzled
    __shared__ float s_red[NPB][4];

    const int tid = threadIdx.x;
    const int node0 = blk * NPB;

#pragma unroll
    for (int it = 0; it < 8; ++it) {
        int idx = it * 256 + tid;          // 2048 float4 groups
        int row = idx >> 5, c4 = idx & 31;
        int n = node0 + row;
        float4 v = (n < n_nodes)
                 ? *reinterpret_cast<const float4*>(&feats[(size_t)n * D + c4 * 4])
                 : make_float4(0.f, 0.f, 0.f, 0.f);
        unsigned short h[4];
        h[0] = f32_to_bf16(v.x); h[1] = f32_to_bf16(v.y);
        h[2] = f32_to_bf16(v.z); h[3] = f32_to_bf16(v.w);
        int byte = row * 256 + c4 * 8;
        byte ^= (row & 7) << 4;
        *reinterpret_cast<ushort4*>((char*)s_tile + byte) = *reinterpret_cast<ushort4*>(h);
    }
    __syncthreads();

    const int wv = tid >> 6, lane = tid & 63;

    f32x4 acc[8];
#pragma unroll
    for (int i = 0; i < 8; ++i) acc[i] = {0.f, 0.f, 0.f, 0.f};

    const int arow = wv * 16 + (lane & 15);
#pragma unroll
    for (int ks = 0; ks < 4; ++ks) {
        int abyte = arow * 256 + ks * 64 + (lane >> 4) * 16;
        abyte ^= (arow & 7) << 4;
        short8 a = *reinterpret_cast<const short8*>((char*)s_tile + abyte);
#pragma unroll
        for (int nt = 0; nt < 8; ++nt) {
            short8 b = *reinterpret_cast<const short8*>(wfrag + ((size_t)(ks * 8 + nt) * 64 + lane) * 8);
            acc[nt] = __builtin_amdgcn_mfma_f32_16x16x32_bf16(a, b, acc[nt], 0, 0, 0);
        }
    }

    // C/D: col = lane&15, row = (lane>>4)*4 + r
#pragma unroll
    for (int nt = 0; nt < 8; ++nt) {
#pragma unroll
        for (int r = 0; r < 4; ++r) {
            int node = node0 + wv * 16 + (lane >> 4) * 4 + r;
            if (node < n_nodes)
                proj[(size_t)node * D + nt * 16 + (lane & 15)] = f32_to_bf16(acc[nt][r]);
        }
    }

    // att scalar: 256 threads = 64 nodes x 4 k-quarters (reads swizzled LDS)
    const int na = tid & 63, kq = tid >> 6;
    float p = 0.f;
#pragma unroll
    for (int k = kq * 32; k < kq * 32 + 32; ++k) {
        int byte = (na * 256 + k * 2) ^ ((na & 7) << 4);
        unsigned short h = *reinterpret_cast<const unsigned short*>((char*)s_tile + byte);
        p += __uint_as_float(((unsigned int)h) << 16) * w_att[wrow + k];
    }
    s_red[na][kq] = p;
    __syncthreads();
    if (tid < NPB) {
        int n = node0 + tid;
        if (n < n_nodes)
            att[n] = s_red[tid][0] + s_red[tid][1] + s_red[tid][2] + s_red[tid][3];
    }
}

// ---------------------------------------------------------------------------
// K_h1: per-block bucket histogram (dst>>5), LDS-binned; bb block-major.
//     512 threads, 4 edges/thread via int4.
// ---------------------------------------------------------------------------
__global__ void __launch_bounds__(512)
hist1_kernel(const int* __restrict__ edst, int* __restrict__ bb,
             int n_edge, int nblk1, int nb1)
{
    __shared__ int bins[MAXBINS];
    const int tid = threadIdx.x, blk = blockIdx.x;
    for (int i = tid; i < nb1; i += 512) bins[i] = 0;
    __syncthreads();
    const int e0 = blk * EPB1 + tid * 4;
    if (e0 + 4 <= n_edge) {
        int4 d4 = *reinterpret_cast<const int4*>(&edst[e0]);
        atomicAdd(&bins[((unsigned)d4.x) >> 5], 1);
        atomicAdd(&bins[((unsigned)d4.y) >> 5], 1);
        atomicAdd(&bins[((unsigned)d4.z) >> 5], 1);
        atomicAdd(&bins[((unsigned)d4.w) >> 5], 1);
    } else {
        for (int e = e0; e < n_edge; ++e)
            atomicAdd(&bins[((unsigned)edst[e]) >> 5], 1);
    }
    __syncthreads();
    for (int i = tid; i < nb1; i += 512) bb[(size_t)blk * nb1 + i] = bins[i];
}

// ---------------------------------------------------------------------------
// K_cs1: chunk sums (read-only, coalesced across adjacent bins).
// ---------------------------------------------------------------------------
__global__ void __launch_bounds__(256)
chunksum_kernel(const int* __restrict__ bb, int* __restrict__ cs,
                int nb1, int nblk1, int cb)
{
    int t = blockIdx.x * 256 + threadIdx.x;
    if (t >= nb1 * NCHUNK) return;
    int c = t / nb1, bin = t - c * nb1;
    int b0 = c * cb, b1 = min(b0 + cb, nblk1);
    int s = 0;
    for (int blk = b0; blk < b1; ++blk)
        s += bb[(size_t)blk * nb1 + bin];
    cs[(size_t)c * nb1 + bin] = s;
}

// ---------------------------------------------------------------------------
// K_ms: midscan (single block): per-bin chunk scan + cross-bin scan.
// ---------------------------------------------------------------------------
__global__ void __launch_bounds__(1024)
midscan_kernel(int* __restrict__ cs, int* __restrict__ binstart,
               int nb1, int n_edge)
{
    __shared__ int s_tot[MAXBINS];
    __shared__ int s_w[16];
    __shared__ int s_total;
    __shared__ int s_carry;
    const int tid = threadIdx.x;
    const int lane = tid & 63, wid = tid >> 6;

    for (int bin = tid; bin < nb1; bin += 1024) {
        int run = 0;
#pragma unroll
        for (int c = 0; c < NCHUNK; ++c) {
            size_t idx = (size_t)c * nb1 + bin;
            int v = cs[idx];
            cs[idx] = run;
            run += v;
        }
        s_tot[bin] = run;
    }
    if (tid == 0) s_carry = 0;
    __syncthreads();

    for (int base = 0; base < nb1; base += 1024) {
        int idx = base + tid;
        int v = (idx < nb1) ? s_tot[idx] : 0;
        int x = v;
#pragma unroll
        for (int off = 1; off < 64; off <<= 1) {
            int y = __shfl_up(x, off);
            if (lane >= off) x += y;
        }
        if (lane == 63) s_w[wid] = x;
        __syncthreads();
        if (tid < 16) {
            int w = s_w[tid];
            int xi = w;
#pragma unroll
            for (int off = 1; off < 16; off <<= 1) {
                int y = __shfl_up(xi, off);
                if (tid >= off) xi += y;
            }
            if (tid == 15) s_total = xi;
            s_w[tid] = xi - w;   // exclusive wave offset
        }
        __syncthreads();
        if (idx < nb1) binstart[idx] = s_carry + s_w[wid] + (x - v);
        __syncthreads();
        if (tid == 0) s_carry += s_total;
        __syncthreads();
    }
    if (tid == 0) binstart[nb1] = n_edge;
}

// ---------------------------------------------------------------------------
// K_cw: chunk write-back, 8-deep batched (alias-broken).
// ---------------------------------------------------------------------------
__global__ void __launch_bounds__(256)
chunkwrite_kernel(int* __restrict__ bb, const int* __restrict__ cs,
                  int nb1, int nblk1, int cb)
{
    int t = blockIdx.x * 256 + threadIdx.x;
    if (t >= nb1 * NCHUNK) return;
    int c = t / nb1, bin = t - c * nb1;
    int b0 = c * cb, b1 = min(b0 + cb, nblk1);
    int carry = cs[(size_t)c * nb1 + bin];
    for (int blk0 = b0; blk0 < b1; blk0 += 8) {
        int v[8];
#pragma unroll
        for (int j = 0; j < 8; ++j) {
            int blk = blk0 + j;
            v[j] = (blk < b1) ? bb[(size_t)blk * nb1 + bin] : 0;
        }
#pragma unroll
        for (int j = 0; j < 8; ++j) {
            int blk = blk0 + j;
            if (blk < b1) bb[(size_t)blk * nb1 + bin] = carry;
            carry += v[j];
        }
    }
}

// ---------------------------------------------------------------------------
// K_p1: phase-split scatter. 512 threads, 4 edges/thread one-shot:
//     batched loads -> 8 independent att gathers -> exps -> 4 LDS atomics
//     -> 4 stores.  meta1 = {src | (dlow<<24), ew, d0, d1}, dlow = d&31.
// ---------------------------------------------------------------------------
__global__ void __launch_bounds__(512)
pass1_kernel(const int* __restrict__ esrc, const int* __restrict__ edst,
             const float* __restrict__ dist,
             const float* __restrict__ src_att, const float* __restrict__ dst_att,
             const float* __restrict__ w_att,
             const int* __restrict__ bb, const int* __restrict__ binstart,
             float4* __restrict__ meta1, int n_edge, int nblk1, int nb1)
{
    __shared__ int cur[MAXBINS];
    const int tid = threadIdx.x, blk = blockIdx.x;
    for (int i = tid; i < nb1; i += 512)
        cur[i] = binstart[i] + bb[(size_t)blk * nb1 + i];
    __syncthreads();

    const float wa0 = w_att[128], wa1 = w_att[129];
    const int e0 = blk * EPB1 + tid * 4;
    if (e0 + 4 <= n_edge) {
        // phase A: batched coalesced loads
        int4 s4 = *reinterpret_cast<const int4*>(&esrc[e0]);
        int4 d4 = *reinterpret_cast<const int4*>(&edst[e0]);
        float4 da = *reinterpret_cast<const float4*>(&dist[2 * (size_t)e0]);
        float4 db = *reinterpret_cast<const float4*>(&dist[2 * (size_t)e0 + 4]);
        // 8 independent gathers
        float sa0 = src_att[s4.x], sa1 = src_att[s4.y];
        float sa2 = src_att[s4.z], sa3 = src_att[s4.w];
        float ta0 = dst_att[d4.x], ta1 = dst_att[d4.y];
        float ta2 = dst_att[d4.z], ta3 = dst_att[d4.w];
        // scores
        float c0 = sa0 + ta0 + da.x * wa0 + da.y * wa1;
        float c1 = sa1 + ta1 + da.z * wa0 + da.w * wa1;
        float c2 = sa2 + ta2 + db.x * wa0 + db.y * wa1;
        float c3 = sa3 + ta3 + db.z * wa0 + db.w * wa1;
        c0 = (c0 >= 0.f) ? c0 : 0.2f * c0;
        c1 = (c1 >= 0.f) ? c1 : 0.2f * c1;
        c2 = (c2 >= 0.f) ? c2 : 0.2f * c2;
        c3 = (c3 >= 0.f) ? c3 : 0.2f * c3;
        float w0 = __expf(c0), w1 = __expf(c1), w2 = __expf(c2), w3 = __expf(c3);
        // phase B: LDS rank atomics
        int p0 = atomicAdd(&cur[((unsigned)d4.x) >> 5], 1);
        int p1 = atomicAdd(&cur[((unsigned)d4.y) >> 5], 1);
        int p2 = atomicAdd(&cur[((unsigned)d4.z) >> 5], 1);
        int p3 = atomicAdd(&cur[((unsigned)d4.w) >> 5], 1);
        // phase C: scattered stores
        meta1[p0] = make_float4(__int_as_float(s4.x | ((d4.x & 31) << 24)), w0, da.x, da.y);
        meta1[p1] = make_float4(__int_as_float(s4.y | ((d4.y & 31) << 24)), w1, da.z, da.w);
        meta1[p2] = make_float4(__int_as_float(s4.z | ((d4.z & 31) << 24)), w2, db.x, db.y);
        meta1[p3] = make_float4(__int_as_float(s4.w | ((d4.w & 31) << 24)), w3, db.z, db.w);
    } else {
        for (int e = e0; e < n_edge; ++e) {
            int s = esrc[e];
            int d = edst[e];
            float2 dd = *reinterpret_cast<const float2*>(&dist[2 * (size_t)e]);
            float sc = src_att[s] + dst_att[d] + dd.x * wa0 + dd.y * wa1;
            sc = (sc >= 0.f) ? sc : 0.2f * sc;
            float ew = __expf(sc);
            int pos = atomicAdd(&cur[((unsigned)d) >> 5], 1);
            meta1[pos] = make_float4(__int_as_float(s | ((d & 31) << 24)), ew, dd.x, dd.y);
        }
    }
}

// ---------------------------------------------------------------------------
// K_p2agg: fused fine-sort (in LDS) + softmax + aggregation.
//     One block per bucket of 32 dsts; 4 waves x 8 dsts; output written direct.
// ---------------------------------------------------------------------------
__global__ void __launch_bounds__(256)
p2agg_kernel(const float4* __restrict__ meta1, const int* __restrict__ binstart,
             const unsigned short* __restrict__ srcp,   // bf16 [n_src,128]
             const unsigned short* __restrict__ dstp,   // bf16 [n_dst,128]
             const float* __restrict__ w_embed,
             float* __restrict__ out, int n_dst)
{
    __shared__ float4 s_meta[CAP];        // 16 KB, fine-sorted bucket meta
    __shared__ int s_cnt[BDST];
    __shared__ int s_ofs[BDST + 1];
    __shared__ int s_cur[BDST];

    const int tid = threadIdx.x;
    const int b = blockIdx.x;
    const int bstart = binstart[b], bend = binstart[b + 1];
    const int bsize = bend - bstart;
    const int lane = tid & 63, wv = tid >> 6;   // 4 waves
    const int c0 = 2 * lane;

    const float2 wd0 = *reinterpret_cast<const float2*>(&w_embed[128 * D + c0]);
    const float2 wd1 = *reinterpret_cast<const float2*>(&w_embed[129 * D + c0]);

    if (tid < BDST) s_cnt[tid] = 0;
    __syncthreads();

    if (bsize <= CAP) {
        // pass A: fine counts (read only the packed word)
        for (int i = tid; i < bsize; i += 256) {
            int bits = __float_as_int(meta1[bstart + i].x);
            atomicAdd(&s_cnt[((unsigned)bits) >> 24], 1);
        }
        __syncthreads();
        // 32-bin exclusive scan (lanes 0..31 of wave 0)
        if (tid < BDST) {
            int v = s_cnt[tid];
            int x = v;
#pragma unroll
            for (int off = 1; off < BDST; off <<= 1) {
                int y = __shfl_up(x, off);
                if (tid >= off) x += y;
            }
            s_ofs[tid] = x - v;
            s_cur[tid] = x - v;
            if (tid == BDST - 1) s_ofs[BDST] = x;
        }
        __syncthreads();
        // pass B: scatter full records into sorted LDS positions
        for (int i = tid; i < bsize; i += 256) {
            float4 m = meta1[bstart + i];
            int dlow = ((unsigned)__float_as_int(m.x)) >> 24;
            int pos = atomicAdd(&s_cur[dlow], 1);
            s_meta[pos] = m;
        }
        __syncthreads();

        // 4 waves x 8 dsts
#define EDGE_ACC(m)                                                               \
        {                                                                         \
            int bits_ = __float_as_int((m).x);                                    \
            unsigned int r_ = *reinterpret_cast<const unsigned int*>(             \
                &srcp[(size_t)(bits_ & 0xFFFFFF) * D + c0]);                      \
            acc0 += (m).y * bf16lo(r_);                                           \
            acc1 += (m).y * bf16hi(r_);                                           \
            sw   += (m).y;                                                        \
            swd0 += (m).y * (m).z;                                                \
            swd1 += (m).y * (m).w;                                                \
        }
#pragma unroll
        for (int k = 0; k < 8; ++k) {
            int dloc = k * 4 + wv;
            int gd = b * BDST + dloc;
            if (gd >= n_dst) continue;
            float2* op = reinterpret_cast<float2*>(&out[(size_t)gd * D + c0]);
            int o0 = s_ofs[dloc], o1 = s_ofs[dloc + 1];
            if (o0 == o1) { *op = make_float2(0.f, 0.f); continue; }

            float acc0 = 0.f, acc1 = 0.f, sw = 0.f, swd0 = 0.f, swd1 = 0.f;
            int j = o0;
            for (; j + 8 <= o1; j += 8) {
                float4 m0 = s_meta[j + 0];
                float4 m1 = s_meta[j + 1];
                float4 m2 = s_meta[j + 2];
                float4 m3 = s_meta[j + 3];
                float4 m4 = s_meta[j + 4];
                float4 m5 = s_meta[j + 5];
                float4 m6 = s_meta[j + 6];
                float4 m7 = s_meta[j + 7];
                EDGE_ACC(m0) EDGE_ACC(m1) EDGE_ACC(m2) EDGE_ACC(m3)
                EDGE_ACC(m4) EDGE_ACC(m5) EDGE_ACC(m6) EDGE_ACC(m7)
            }
            for (; j < o1; ++j) {
                float4 m0 = s_meta[j];
                EDGE_ACC(m0)
            }
            float inv = 1.f / sw;
            unsigned int rd = *reinterpret_cast<const unsigned int*>(&dstp[(size_t)gd * D + c0]);
            float ov0 = (acc0 + swd0 * wd0.x + swd1 * wd1.x) * inv + bf16lo(rd);
            float ov1 = (acc1 + swd0 * wd0.y + swd1 * wd1.y) * inv + bf16hi(rd);
            *op = make_float2(fmaxf(ov0, 0.f), fmaxf(ov1, 0.f));
        }
#undef EDGE_ACC
    } else {
        // robust slow path (never taken at these sizes): chunked scan
        float acc0[8], acc1[8], sw[8], s0[8], s1[8];
        for (int k = 0; k < 8; ++k) { acc0[k] = acc1[k] = sw[k] = s0[k] = s1[k] = 0.f; }
        for (int cs2 = bstart; cs2 < bend; cs2 += CAP) {
            int n = min(CAP, bend - cs2);
            __syncthreads();
            for (int i = tid; i < n; i += 256) s_meta[i] = meta1[cs2 + i];
            __syncthreads();
            for (int k = 0; k < 8; ++k) {
                int dloc = k * 4 + wv;
                for (int i = 0; i < n; ++i) {
                    float4 m = s_meta[i];
                    int bits = __float_as_int(m.x);
                    if ((int)(((unsigned)bits) >> 24) == dloc) {
                        unsigned int r = *reinterpret_cast<const unsigned int*>(
                            &srcp[(size_t)(bits & 0xFFFFFF) * D + c0]);
                        acc0[k] += m.y * bf16lo(r);
                        acc1[k] += m.y * bf16hi(r);
                        sw[k] += m.y;
                        s0[k] += m.y * m.z;
                        s1[k] += m.y * m.w;
                    }
                }
            }
        }
        for (int k = 0; k < 8; ++k) {
            int dloc = k * 4 + wv;
            int gd = b * BDST + dloc;
            if (gd >= n_dst) continue;
            float2* op = reinterpret_cast<float2*>(&out[(size_t)gd * D + c0]);
            if (sw[k] == 0.f) { *op = make_float2(0.f, 0.f); continue; }
            float inv = 1.f / sw[k];
            unsigned int rd = *reinterpret_cast<const unsigned int*>(&dstp[(size_t)gd * D + c0]);
            float ov0 = (acc0[k] + s0[k] * wd0.x + s1[k] * wd1.x) * inv + bf16lo(rd);
            float ov1 = (acc1[k] + s0[k] * wd0.y + s1[k] * wd1.y) * inv + bf16hi(rd);
            *op = make_float2(fmaxf(ov0, 0.f), fmaxf(ov1, 0.f));
        }
    }
}

// ---------------------------------------------------------------------------
extern "C" void kernel_launch(void* const* d_in, const int* in_sizes, int n_in,
                              void* d_out, int out_size, void* d_ws, size_t ws_size,
                              hipStream_t stream)
{
    const float* src_feat = (const float*)d_in[0];   // [N_SRC,128]
    const int*   esrc     = (const int*)d_in[1];     // [E]
    const float* dst_feat = (const float*)d_in[2];   // [N_DST,128]
    const int*   edst     = (const int*)d_in[3];     // [E]
    const float* dist     = (const float*)d_in[4];   // [E,2]
    const float* w_att    = (const float*)d_in[5];   // [258]
    const float* w_embed  = (const float*)d_in[6];   // [258,128]

    const int n_src  = in_sizes[0] / D;
    const int n_edge = in_sizes[1];
    const int n_dst  = in_sizes[2] / D;

    const int nb1   = (n_dst + BDST - 1) / BDST;     // buckets (1563)
    const int nblk1 = (n_edge + EPB1 - 1) / EPB1;    // pass-1 blocks (391)
    const int cb    = (nblk1 + NCHUNK - 1) / NCHUNK; // blocks per scan chunk (49)
    const size_t n1 = (size_t)nb1 * nblk1;

    // ---- workspace carve-up (256B-aligned) ----
    char* p = (char*)d_ws;
    auto carve = [&p](size_t bytes) {
        char* r = p;
        p += (bytes + 255) & ~size_t(255);
        return r;
    };
    unsigned short* src_projb = (unsigned short*)carve((size_t)n_src * D * 2);  // bf16
    unsigned short* dst_projb = (unsigned short*)carve((size_t)n_dst * D * 2);  // bf16
    float* src_att   = (float*)carve((size_t)n_src * 4);
    float* dst_att   = (float*)carve((size_t)n_dst * 4);
    int*   bb        = (int*)carve(n1 * 4);
    int*   cs        = (int*)carve((size_t)NCHUNK * nb1 * 4);
    int*   binstart  = (int*)carve((size_t)(nb1 + 1) * 4);
    unsigned short* w_frag = (unsigned short*)carve(2 * 4 * 8 * 64 * 8 * 2);  // 64 KB
    float4* meta1    = (float4*)carve((size_t)n_edge * 16);
    (void)ws_size;

    // K0: W -> bf16 fragment layout
    wconv_kernel<<<16, 256, 0, stream>>>(w_embed, w_frag);

    // K1: fused MFMA node projections
    const int nblk_src = (n_src + NPB - 1) / NPB;
    const int nblk_dst = (n_dst + NPB - 1) / NPB;
    proj_both_kernel<<<nblk_src + nblk_dst, 256, 0, stream>>>(
        src_feat, dst_feat, w_frag, w_att, n_src, n_dst, nblk_src,
        src_projb, dst_projb, src_att, dst_att);

    // K_h1: bucket histogram per pass1-block (block-major, coalesced)
    hist1_kernel<<<nblk1, 512, 0, stream>>>(edst, bb, n_edge, nblk1, nb1);

    // K_cs1 / K_ms / K_cw: parallel column scan of bb + binstart
    const int nthr_cs = nb1 * NCHUNK;
    chunksum_kernel<<<(nthr_cs + 255) / 256, 256, 0, stream>>>(bb, cs, nb1, nblk1, cb);
    midscan_kernel<<<1, 1024, 0, stream>>>(cs, binstart, nb1, n_edge);
    chunkwrite_kernel<<<(nthr_cs + 255) / 256, 256, 0, stream>>>(bb, cs, nb1, nblk1, cb);

    // K_p1: score/exp + bucket scatter (512 thr, phase-split ILP)
    pass1_kernel<<<nblk1, 512, 0, stream>>>(esrc, edst, dist, src_att, dst_att,
                                            w_att, bb, binstart, meta1,
                                            n_edge, nblk1, nb1);

    // K_p2agg: fused fine-sort + softmax + aggregation
    p2agg_kernel<<<nb1, 256, 0, stream>>>(meta1, binstart, src_projb, dst_projb,
                                          w_embed, (float*)d_out, n_dst);
}